// Round 11
// baseline (13265.993 us; speedup 1.0000x reference)
//
#include <hip/hip_runtime.h>
#include <hip/hip_cooperative_groups.h>

namespace cg = cooperative_groups;

// LSTM_HEAD: MFMA hi/lo-split gate GEMM, 167-step recurrence.
// Round 11: attack Round-10 counters (VGPR=40 -> A-loads serialized; 21MB/step
// HBM refetch -> W restaged every dispatch).
//  1) A-fragment loads via asm volatile global_load_dwordx4 (un-sinkable),
//     36 in flight per K-half, one s_waitcnt vmcnt(0) + sched_barrier(0).
//  2) Cooperative persistent kernel retried at the proven 75KB LDS (W staged
//     once, grid.sync per step); rc-checked fallback = Round-10 per-step path.

#define HIDDEN 512
#define SEQ    168
#define NSTEP  167
#define BS     1024
#define CTX    64
#define KM     576       // MFMA K: x cols 0-63 | h cols 64-575 (W rows 66..577)
#define KP     584       // LDS k-pitch (ushorts): 1168B rows -> conflict-free b128
#define MTILE  128       // batches per WG
#define SGRID  512       // 64 unit-tiles x 8 batch-tiles
#define PGRID  256
#define NTHR   256
#define WTELEM (2 * 32 * KP)          // 37,376 ushorts per nt tile (74,752 B)

typedef __attribute__((ext_vector_type(8))) short s16x8;
typedef __attribute__((ext_vector_type(4))) float f32x4;

static __device__ __forceinline__ unsigned short bf16_rne(float f) {
    union { float f; unsigned int u; } v; v.f = f;
    unsigned int r = v.u + 0x7FFFu + ((v.u >> 16) & 1u);
    return (unsigned short)(r >> 16);
}
static __device__ __forceinline__ float bf16_to_f(unsigned short h) {
    union { float f; unsigned int u; } v; v.u = ((unsigned int)h) << 16;
    return v.f;
}
static __device__ __forceinline__ float sigmoid_(float x) {
    x = fminf(fmaxf(x, -80.f), 80.f);
    return 1.0f / (1.0f + __expf(-x));
}
static __device__ __forceinline__ float tanh_(float x) {
    float ax = fminf(fabsf(x), 40.f);
    float e = __expf(-2.0f * ax);
    float r = (1.0f - e) / (1.0f + e);
    return copysignf(r, x);
}
// Un-sinkable 16B global load (volatile asm keeps issue order; compiler's
// heuristics can't serialize it the way they did the C++ loads -> VGPR=40).
static __device__ __forceinline__ s16x8 gload16(const unsigned short* p) {
    s16x8 r;
    asm volatile("global_load_dwordx4 %0, %1, off" : "=v"(r) : "v"(p));
    return r;
}

// ---- init: out = bo, c = 0, A[parity0] = {x_dyn[:,0] | h0=0} ----
__global__ void lstm_prep(const float* __restrict__ x_dyn, float* __restrict__ out,
                          const float* __restrict__ bo_p,
                          unsigned short* __restrict__ aHi, unsigned short* __restrict__ aLo,
                          float* __restrict__ cst)
{
    const int gthr = blockIdx.x * NTHR + threadIdx.x;
    const int gstr = PGRID * NTHR;
    const float bo = *bo_p;
    for (int i = gthr; i < BS * NSTEP; i += gstr) out[i] = bo;
    for (int i = gthr; i < BS * HIDDEN; i += gstr) cst[i] = 0.f;
    for (int i = gthr; i < BS * 256; i += gstr) {        // h-cols 64..575 (256 uints/row)
        const int b = i >> 8, j = i & 255;
        ((unsigned int*)aHi)[b * 288 + 32 + j] = 0u;
        ((unsigned int*)aLo)[b * 288 + 32 + j] = 0u;
    }
    for (int i = gthr; i < BS * CTX; i += gstr) {        // x-cols 0..63 at t=0
        const int b = i >> 6, col = i & 63;
        const float v = x_dyn[(size_t)b * SEQ * CTX + col];
        const unsigned short hi = bf16_rne(v);
        aHi[(size_t)b * KM + col] = hi;
        aLo[(size_t)b * KM + col] = bf16_rne(v - bf16_to_f(hi));
    }
}

// ---- one-time: W (fp32) -> per-nt-tile bf16 hi/lo planes, padded LDS layout ----
__global__ void wprep(const float* __restrict__ Wg, unsigned short* __restrict__ wpl)
{
    const int gthr = blockIdx.x * NTHR + threadIdx.x;
    const int gstr = PGRID * NTHR;
    for (int i = gthr; i < 64 * 32 * KP; i += gstr) {
        const int kp = i % KP;
        const int c  = (i / KP) & 31;
        const int nt = i / (KP * 32);
        unsigned short hi = 0, lo = 0;
        if (kp < KM) {
            const int wrow = (kp < 64) ? kp : (kp + 2);  // skip rows 64,65 (fixup)
            const int wcol = (2 * (c >> 4) + ((c >> 3) & 1)) * 512 + nt * 8 + (c & 7);
            const float v = Wg[(size_t)wrow * 2048 + wcol];
            hi = bf16_rne(v);
            lo = bf16_rne(v - bf16_to_f(hi));
        }
        const size_t base = (size_t)nt * WTELEM + (size_t)c * KP + kp;
        wpl[base] = hi;                       // plane 0
        wpl[base + 32 * KP] = lo;             // plane 1
    }
}

// ---- W tile -> LDS via global_load_lds (proven Round 10) ----
static __device__ __forceinline__ void stage_w(const unsigned short* __restrict__ wpl,
                                               unsigned char* smem_raw, int nt, int wv, int lane)
{
    const unsigned short* wsrc = wpl + (size_t)nt * WTELEM;
    for (int c = wv; c < 73; c += 4) {
        __builtin_amdgcn_global_load_lds(
            (const __attribute__((address_space(1))) void*)(wsrc + c * 512 + lane * 8),
            (__attribute__((address_space(3))) void*)(smem_raw + c * 1024),
            16, 0, 0);
    }
}

// ---- one LSTM step from a64s-staging onward (W already in/heading to LDS) ----
static __device__ __forceinline__ void step_core(
    int t, int twin, int tid, int nt, int m0,
    const float* __restrict__ x_dyn, const float* __restrict__ y_flow,
    float* __restrict__ out, float* __restrict__ cst,
    unsigned short* __restrict__ aHi, unsigned short* __restrict__ aLo,
    const unsigned short* whi, const unsigned short* wlo, float* a64s,
    const float* w64c, const float* w65c, const float* biasc,
    float wo_u, int u, int wv, int ln15, int kg, bool lo_half,
    size_t aoff0, size_t aoff1)
{
    const int par = t & 1, pn = par ^ 1;
    const unsigned short* aH = aHi + (size_t)par * BS * KM;
    const unsigned short* aL = aLo + (size_t)par * BS * KM;
    unsigned short* nH = aHi + (size_t)pn * BS * KM;
    unsigned short* nL = aLo + (size_t)pn * BS * KM;
    const float hv = (t < twin) ? 0.f : (float)(t - twin + 1) * (1.f / 24.f);

    // stage y/last column for this WG's 128 batches
    if (tid < MTILE) {
        const int b = m0 + tid;
        float v;
        if (t < twin) v = y_flow[(size_t)b * SEQ + t];
        else if (t > 0) v = __hip_atomic_load(&out[(size_t)b * NSTEP + (t - 1)],
                                              __ATOMIC_RELAXED, __HIP_MEMORY_SCOPE_AGENT);
        else v = 0.f;
        a64s[tid] = v;
    }
    __syncthreads();   // drains W global_load_lds (vmcnt) + a64s lgkm

    // x-refresh for step t+1 into other parity (2 batches per nt-WG)
    if (tid < 128) {
        const int b = m0 + nt * 2 + (tid >> 6), col = tid & 63;
        const float v = x_dyn[((size_t)b * SEQ + (t + 1)) * CTX + col];
        const unsigned short hi = bf16_rne(v);
        nH[(size_t)b * KM + col] = hi;
        nL[(size_t)b * KM + col] = bf16_rne(v - bf16_to_f(hi));
    }

    // ---- gate GEMM: 3-pass hi/lo bf16 MFMA over K=576, asm-batched A loads ----
    float basec2[2];
    basec2[0] = fmaf(hv, w65c[0], biasc[0]);
    basec2[1] = fmaf(hv, w65c[1], biasc[1]);

    f32x4 acc[2][2];
    #pragma unroll
    for (int ms = 0; ms < 2; ++ms)
        #pragma unroll
        for (int ns = 0; ns < 2; ++ns) acc[ms][ns] = (f32x4){0.f, 0.f, 0.f, 0.f};

    #pragma unroll
    for (int half = 0; half < 2; ++half) {
        s16x8 Ah[9][2], Al[9][2];
        #pragma unroll
        for (int j = 0; j < 9; ++j) {
            const size_t k0 = (size_t)(half * 9 + j) * 32;
            Ah[j][0] = gload16(aH + aoff0 + k0);
            Ah[j][1] = gload16(aH + aoff1 + k0);
            Al[j][0] = gload16(aL + aoff0 + k0);
            Al[j][1] = gload16(aL + aoff1 + k0);
        }
        asm volatile("s_waitcnt vmcnt(0)" ::: "memory");
        __builtin_amdgcn_sched_barrier(0);   // rule #18: fence MFMA hoisting
        #pragma unroll
        for (int j = 0; j < 9; ++j) {
            const int k0 = (half * 9 + j) * 32;
            s16x8 bh[2], bl[2];
            #pragma unroll
            for (int ns = 0; ns < 2; ++ns) {
                const int boff = (ns * 16 + ln15) * KP + k0 + kg * 8;
                bh[ns] = *(const s16x8*)(whi + boff);
                bl[ns] = *(const s16x8*)(wlo + boff);
            }
            #pragma unroll
            for (int ns = 0; ns < 2; ++ns)
                #pragma unroll
                for (int ms = 0; ms < 2; ++ms) {
                    acc[ms][ns] = __builtin_amdgcn_mfma_f32_16x16x32_bf16(Ah[j][ms], bh[ns], acc[ms][ns], 0, 0, 0);
                    acc[ms][ns] = __builtin_amdgcn_mfma_f32_16x16x32_bf16(Ah[j][ms], bl[ns], acc[ms][ns], 0, 0, 0);
                    acc[ms][ns] = __builtin_amdgcn_mfma_f32_16x16x32_bf16(Al[j][ms], bh[ns], acc[ms][ns], 0, 0, 0);
                }
        }
    }

    // ---- fixup + gate-transpose (xor 8) + cell + h/pred ----
    #pragma unroll
    for (int ms = 0; ms < 2; ++ms) {
        #pragma unroll
        for (int r = 0; r < 4; ++r) {
            const int rl = wv * 32 + ms * 16 + kg * 4 + r;   // C/D: row=(lane>>4)*4+reg
            const int b = m0 + rl;
            const float a64v = a64s[rl];
            const float pre0 = acc[ms][0][r] + fmaf(a64v, w64c[0], basec2[0]);
            const float pre1 = acc[ms][1][r] + fmaf(a64v, w64c[1], basec2[1]);
            const float q0 = __shfl_xor(pre0, 8, 16);
            const float q1 = __shfl_xor(pre1, 8, 16);
            const float pi = lo_half ? pre0 : q0;
            const float pf = lo_half ? q0 : pre0;
            const float pg = lo_half ? pre1 : q1;
            const float po = lo_half ? q1 : pre1;
            const float i_ = sigmoid_(pi);
            const float f_ = sigmoid_(pf);
            const float g_ = tanh_(pg);
            const float o_ = sigmoid_(po);
            const size_t ci = (size_t)b * HIDDEN + u;
            const float c = f_ * cst[ci] + i_ * g_;
            const float h = o_ * tanh_(c);
            if (lo_half) {   // lanes l and l^8 computed identical (b,u) results
                cst[ci] = c;
                const unsigned short hh = bf16_rne(h);
                nH[(size_t)b * KM + 64 + u] = hh;
                nL[(size_t)b * KM + 64 + u] = bf16_rne(h - bf16_to_f(hh));
            }
            float p = lo_half ? h * wo_u : 0.f;
            p += __shfl_xor(p, 1, 16);
            p += __shfl_xor(p, 2, 16);
            p += __shfl_xor(p, 4, 16);
            p += __shfl_xor(p, 8, 16);
            if (ln15 == 0) atomicAdd(&out[(size_t)b * NSTEP + t], p);
        }
    }
}

#define LANE_SETUP                                                              \
    const int tid = threadIdx.x, bid = blockIdx.x;                              \
    const int nt = bid >> 3;              /* unit tile: 8 units, 32 cols */     \
    const int m0 = (bid & 7) * MTILE;     /* batch tile; bid%8 = XCD */         \
    const int lane = tid & 63, wv = tid >> 6, ln15 = lane & 15, kg = lane >> 4; \
    const int twin = *twin_p;                                                   \
    float w64c[2], w65c[2], biasc[2];                                           \
    _Pragma("unroll")                                                           \
    for (int ns = 0; ns < 2; ++ns) {                                            \
        const int wcol = (2 * ns + (ln15 >> 3)) * 512 + nt * 8 + (ln15 & 7);    \
        w64c[ns]  = Wg[(size_t)64 * 2048 + wcol];                               \
        w65c[ns]  = Wg[(size_t)65 * 2048 + wcol];                               \
        biasc[ns] = bias[wcol];                                                 \
    }                                                                           \
    const int u = nt * 8 + (ln15 & 7);                                          \
    const float wo_u = Wo[u];                                                   \
    const bool lo_half = (ln15 < 8);                                            \
    const size_t aoff0 = (size_t)(m0 + wv * 32 + ln15) * KM + kg * 8;           \
    const size_t aoff1 = aoff0 + (size_t)16 * KM;

__global__ __launch_bounds__(NTHR, 2)
void lstm_persist(const float* __restrict__ x_dyn, const float* __restrict__ y_flow,
                  const float* __restrict__ Wg, const float* __restrict__ bias,
                  const float* __restrict__ Wo, const int* __restrict__ twin_p,
                  float* __restrict__ out, unsigned short* __restrict__ aHi,
                  unsigned short* __restrict__ aLo, float* __restrict__ cst,
                  const unsigned short* __restrict__ wpl)
{
    cg::grid_group grid = cg::this_grid();
    extern __shared__ unsigned char smem_raw[];
    unsigned short* whi = (unsigned short*)smem_raw;     // [32][KP]
    unsigned short* wlo = whi + 32 * KP;                 // [32][KP]
    float* a64s = (float*)(wlo + 32 * KP);               // [128]

    LANE_SETUP

    stage_w(wpl, smem_raw, nt, wv, lane);   // once; step 0's __syncthreads drains

    for (int t = 0; t < NSTEP; ++t) {
        step_core(t, twin, tid, nt, m0, x_dyn, y_flow, out, cst, aHi, aLo,
                  whi, wlo, a64s, w64c, w65c, biasc, wo_u, u, wv, ln15, kg,
                  lo_half, aoff0, aoff1);
        if (t != NSTEP - 1) grid.sync();
    }
}

__global__ __launch_bounds__(NTHR, 2)
void lstm_step(const float* __restrict__ x_dyn, const float* __restrict__ y_flow,
               const float* __restrict__ Wg, const float* __restrict__ bias,
               const float* __restrict__ Wo, const int* __restrict__ twin_p,
               float* __restrict__ out, unsigned short* __restrict__ aHi,
               unsigned short* __restrict__ aLo, float* __restrict__ cst,
               const unsigned short* __restrict__ wpl, int t)
{
    extern __shared__ unsigned char smem_raw[];
    unsigned short* whi = (unsigned short*)smem_raw;
    unsigned short* wlo = whi + 32 * KP;
    float* a64s = (float*)(wlo + 32 * KP);

    LANE_SETUP

    stage_w(wpl, smem_raw, nt, wv, lane);   // step_core's __syncthreads drains

    step_core(t, twin, tid, nt, m0, x_dyn, y_flow, out, cst, aHi, aLo,
              whi, wlo, a64s, w64c, w65c, biasc, wo_u, u, wv, ln15, kg,
              lo_half, aoff0, aoff1);
}

extern "C" void kernel_launch(void* const* d_in, const int* in_sizes, int n_in,
                              void* d_out, int out_size, void* d_ws, size_t ws_size,
                              hipStream_t stream) {
    (void)in_sizes; (void)n_in; (void)out_size; (void)ws_size;
    const float* x_dyn  = (const float*)d_in[0];
    const float* y_flow = (const float*)d_in[1];
    const float* Wg     = (const float*)d_in[2];
    const float* bias   = (const float*)d_in[3];
    const float* Wo     = (const float*)d_in[4];
    const float* bo     = (const float*)d_in[5];
    const int*   twin   = (const int*)d_in[6];
    float* out = (float*)d_out;

    unsigned short* aHi = (unsigned short*)d_ws;                 // [2][BS][KM]
    unsigned short* aLo = aHi + (size_t)2 * BS * KM;             // [2][BS][KM]
    float* cst = (float*)(aLo + (size_t)2 * BS * KM);            // [BS][HIDDEN]
    unsigned short* wpl = (unsigned short*)(cst + (size_t)BS * HIDDEN);  // [64][2][32][KP]

    const unsigned int smem = (2u * 32u * KP) * 2u + MTILE * 4u; // 75,264 B

    (void)hipFuncSetAttribute((const void*)lstm_persist,
                              hipFuncAttributeMaxDynamicSharedMemorySize, (int)smem);
    (void)hipFuncSetAttribute((const void*)lstm_step,
                              hipFuncAttributeMaxDynamicSharedMemorySize, (int)smem);

    lstm_prep<<<dim3(PGRID), dim3(NTHR), 0, stream>>>(x_dyn, out, bo, aHi, aLo, cst);
    wprep<<<dim3(PGRID), dim3(NTHR), 0, stream>>>(Wg, wpl);

    void* kargs[] = {(void*)&x_dyn, (void*)&y_flow, (void*)&Wg, (void*)&bias,
                     (void*)&Wo, (void*)&twin, (void*)&out,
                     (void*)&aHi, (void*)&aLo, (void*)&cst, (void*)&wpl};
    hipError_t rc = hipLaunchCooperativeKernel((const void*)lstm_persist,
                                               dim3(SGRID), dim3(NTHR), kargs,
                                               smem, stream);
    if (rc != hipSuccess) {
        // Fallback: per-step normal launches (kernel boundary = grid sync).
        for (int t = 0; t < NSTEP; ++t) {
            lstm_step<<<dim3(SGRID), dim3(NTHR), smem, stream>>>(
                x_dyn, y_flow, Wg, bias, Wo, twin, out, aHi, aLo, cst, wpl, t);
        }
    }
}